// Round 2
// baseline (633.762 us; speedup 1.0000x reference)
//
#include <hip/hip_runtime.h>

#define NB    65536   // batch rows
#define DIN   768     // hidden dim
#define DCB   192     // codebook hidden
#define KCL   100     // clusters
#define NJ    112     // padded j (100 scores + col100=mu + pad)

// workspace layout (float offsets) — total 172,116 floats = 688,464 B
// (stays under the 806 KB footprint proven by the 540us session)
#define OFF_S    0        // 100*192 f32 (persists: kB slow path + kC)
#define OFF_CS   19200    // 112
#define OFF_U    19312    // 112
#define OFF_T    19424    // 112
#define OFF_ZH   19536    // 100*768 f32
#define OFF_FLAG 96336    // 1 int
#define OFF_CNT  96337    // 1 int (flagged-row count)
#define OFF_MTH  96340    // 112*768 f16 = 43008 floats (byte 385360, 16B aligned)
#define OFF_KTIL 96340    // aliases Mth region: ktil dead before kA3 writes Mth
#define OFF_LIST 139348   // 65536 ushort row-ids = 32768 floats -> ends 172116

#define MARGIN 1e-4f      // ~14 sigma of f16-MFMA score error; flags ~5% of rows
#define MTSC   64.0f      // Mt pre-scale (argmax-invariant, keeps f16 normal-range)
#define SCINV  0.015625f

typedef __attribute__((ext_vector_type(8))) _Float16 half8;
typedef __attribute__((ext_vector_type(4))) float    f32x4;

// ---------------- setup kernels (small, f64 accumulation, coalesced) ----------------

// ktil[j][i] = sum_m cb[j,m]*Wk[i,m];  also init flag=0, cnt=0
__global__ void kA1(const float* __restrict__ cb, const float* __restrict__ Wk,
                    float* __restrict__ ktil, int* __restrict__ flag,
                    int* __restrict__ cnt) {
  __shared__ float cbrow[DCB];
  int j = blockIdx.x, i = threadIdx.x;  // block=192
  if (j == 0 && i == 0) { *flag = 0; *cnt = 0; }
  cbrow[i] = cb[j*DCB + i];
  __syncthreads();
  const float4* wr = (const float4*)&Wk[(size_t)i * DCB];
  double s0 = 0.0, s1 = 0.0;
  #pragma unroll 4
  for (int m4 = 0; m4 < DCB/4; m4++) {
    float4 w = wr[m4];
    s0 += (double)w.x * (double)cbrow[m4*4+0] + (double)w.z * (double)cbrow[m4*4+2];
    s1 += (double)w.y * (double)cbrow[m4*4+1] + (double)w.w * (double)cbrow[m4*4+3];
  }
  ktil[j*DCB+i] = (float)(s0 + s1);
}

// A[j,c] = sum_i Wq[i,c]*ktil[j,i];  S=ln_g*A;  csum[j]=sum_c S;  t[j]=sum_c ln_b*A;
// u[j]=sum_c b_low*S;  u[100]=sum(b_low)/192; pads. flag|=any t!=0.
__global__ void kA2(const float* __restrict__ Wq, const float* __restrict__ ktil,
                    const float* __restrict__ ln_g, const float* __restrict__ ln_b,
                    const float* __restrict__ b_low,
                    float* __restrict__ S, float* __restrict__ csum,
                    float* __restrict__ tv, float* __restrict__ u,
                    int* __restrict__ flag) {
  __shared__ float krow[DCB];
  __shared__ double red[DCB];
  int j = blockIdx.x, c = threadIdx.x;  // block=192
  krow[c] = ktil[j*DCB + c];
  __syncthreads();
  double a0 = 0.0, a1 = 0.0;
  #pragma unroll 4
  for (int i = 0; i < DCB; i += 2) {
    a0 += (double)Wq[i*DCB+c]     * (double)krow[i];
    a1 += (double)Wq[(i+1)*DCB+c] * (double)krow[i+1];
  }
  double a = a0 + a1;
  float Sv = ln_g[c] * (float)a;
  S[j*DCB+c] = Sv;

  red[c] = (double)Sv; __syncthreads();
  if (c == 0) {
    double p0=0,p1=0,p2=0,p3=0;
    for (int i = 0; i < DCB; i += 4) { p0+=red[i]; p1+=red[i+1]; p2+=red[i+2]; p3+=red[i+3]; }
    csum[j] = (float)(p0+p1+p2+p3);
  }
  __syncthreads();
  red[c] = (double)ln_b[c] * a; __syncthreads();
  if (c == 0) {
    double p0=0,p1=0,p2=0,p3=0;
    for (int i = 0; i < DCB; i += 4) { p0+=red[i]; p1+=red[i+1]; p2+=red[i+2]; p3+=red[i+3]; }
    float tf = (float)(p0+p1+p2+p3); tv[j] = tf;
    if (tf != 0.0f) atomicOr(flag, 1);
  }
  __syncthreads();
  red[c] = (double)b_low[c] * (double)Sv; __syncthreads();
  if (c == 0) {
    double p0=0,p1=0,p2=0,p3=0;
    for (int i = 0; i < DCB; i += 4) { p0+=red[i]; p1+=red[i+1]; p2+=red[i+2]; p3+=red[i+3]; }
    u[j] = (float)(p0+p1+p2+p3);
  }
  __syncthreads();
  if (j == 0) {
    red[c] = (double)b_low[c]; __syncthreads();
    if (c == 0) {
      double p0=0,p1=0,p2=0,p3=0;
      for (int i = 0; i < DCB; i += 4) { p0+=red[i]; p1+=red[i+1]; p2+=red[i+2]; p3+=red[i+3]; }
      u[KCL] = (float)((p0+p1+p2+p3) / (double)DCB);
      for (int p = KCL+1; p < NJ; p++) u[p] = 0.f;
      for (int p = KCL;   p < NJ; p++) { csum[p] = 0.f; tv[p] = 0.f; }
    }
  }
}

// Mth[j][d] = f16( MTSC * sum_c W_low[c,d]*S[j,c] ); row 100 = colmean of W_low; pads = 0
__global__ void kA3(const float* __restrict__ W_low, const float* __restrict__ S,
                    _Float16* __restrict__ Mth) {
  __shared__ float srow[DCB];
  int j = blockIdx.x, t = threadIdx.x;  // block=256
  if (j < KCL && t < DCB) srow[t] = S[j*DCB + t];
  __syncthreads();
  float v0, v1, v2;
  if (j < KCL) {
    double a0 = 0.0, a1 = 0.0, a2 = 0.0;
    for (int c = 0; c < DCB; c++) {
      float sc = srow[c];
      a0 += (double)W_low[(size_t)c*DIN + t]       * (double)sc;
      a1 += (double)W_low[(size_t)c*DIN + t + 256] * (double)sc;
      a2 += (double)W_low[(size_t)c*DIN + t + 512] * (double)sc;
    }
    v0 = (float)a0; v1 = (float)a1; v2 = (float)a2;
  } else if (j == KCL) {
    double a0 = 0.0, a1 = 0.0, a2 = 0.0;
    for (int c = 0; c < DCB; c++) {
      a0 += (double)W_low[(size_t)c*DIN + t];
      a1 += (double)W_low[(size_t)c*DIN + t + 256];
      a2 += (double)W_low[(size_t)c*DIN + t + 512];
    }
    v0 = (float)(a0 / (double)DCB);
    v1 = (float)(a1 / (double)DCB);
    v2 = (float)(a2 / (double)DCB);
  } else {
    v0 = v1 = v2 = 0.f;
  }
  Mth[(size_t)j*DIN + t]       = (_Float16)(v0 * MTSC);
  Mth[(size_t)j*DIN + t + 256] = (_Float16)(v1 * MTSC);
  Mth[(size_t)j*DIN + t + 512] = (_Float16)(v2 * MTSC);
}

// ZH[j][d] = sum_c cb[j,c]*W_high[d,c] + b_high[d]
__global__ void kA4(const float* __restrict__ cb, const float* __restrict__ W_high,
                    const float* __restrict__ b_high, float* __restrict__ ZH) {
  __shared__ float cbrow[DCB];
  int j = blockIdx.x, t = threadIdx.x;  // block=256
  if (t < DCB) cbrow[t] = cb[j*DCB + t];
  __syncthreads();
  #pragma unroll
  for (int kd = 0; kd < 3; kd++) {
    int d = t + 256*kd;
    const float4* wr = (const float4*)&W_high[(size_t)d * DCB];
    double s0 = 0.0, s1 = 0.0;
    #pragma unroll 4
    for (int c4 = 0; c4 < DCB/4; c4++) {
      float4 w = wr[c4];
      s0 += (double)w.x * (double)cbrow[c4*4+0] + (double)w.z * (double)cbrow[c4*4+2];
      s1 += (double)w.y * (double)cbrow[c4*4+1] + (double)w.w * (double)cbrow[c4*4+3];
    }
    ZH[(size_t)j*DIN + d] = (float)(s0 + s1 + (double)b_high[d]);
  }
}

// ---------------- main kernel: MFMA scores, wave-autonomous, no LDS/barriers ----------------
// 1024 blocks x 256 threads (4 waves). Wave owns 16 rows x all 112 cols.
// A-frag: lane holds hidden[R + (lane&15)][32t + (lane>>4)*8 + e] (f32->f16 in reg)
// B-frag: lane holds Mth[nj*16 + (lane&15)][32t + (lane>>4)*8 + e]
// D: row = (lane>>4)*4 + r, col = nj*16 + (lane&15)   [guide §3, m89-verified family]
__global__ __launch_bounds__(256, 3)
void kB(const float* __restrict__ hidden, float* __restrict__ out,
        const _Float16* __restrict__ Mth, const float* __restrict__ u,
        const float* __restrict__ csum, const float* __restrict__ ZH,
        const int* __restrict__ flag, int* __restrict__ cnt,
        unsigned short* __restrict__ list,
        const float* __restrict__ S, const float* __restrict__ tv,
        const float* __restrict__ W_low, const float* __restrict__ b_low) {
  const int tid = threadIdx.x;
  if (*flag == 0) {
    const int lane = tid & 63;
    const int wv   = tid >> 6;
    const int lj   = lane & 15, lk = lane >> 4;
    const int R    = blockIdx.x * 64 + wv * 16;

    const float*    Ap = hidden + (size_t)(R + lj) * DIN + lk * 8;
    const _Float16* Bp = Mth    + (size_t)lj       * DIN + lk * 8;

    f32x4 acc[7];
    #pragma unroll
    for (int nj = 0; nj < 7; nj++) acc[nj] = (f32x4){0.f, 0.f, 0.f, 0.f};

    float4 a0 = *(const float4*)(Ap);
    float4 a1 = *(const float4*)(Ap + 4);
    half8 b[7];
    #pragma unroll
    for (int nj = 0; nj < 7; nj++) b[nj] = *(const half8*)(Bp + nj * 16 * DIN);

    #pragma unroll
    for (int t = 0; t < 24; t++) {
      float4 na0, na1; half8 nb[7];
      if (t < 23) {                       // 1-deep register prefetch of step t+1
        const float* Ap2 = Ap + (t + 1) * 32;
        na0 = *(const float4*)(Ap2);
        na1 = *(const float4*)(Ap2 + 4);
        const _Float16* Bp2 = Bp + (t + 1) * 32;
        #pragma unroll
        for (int nj = 0; nj < 7; nj++) nb[nj] = *(const half8*)(Bp2 + nj * 16 * DIN);
      }
      half8 ah;
      ah[0] = (_Float16)a0.x; ah[1] = (_Float16)a0.y;
      ah[2] = (_Float16)a0.z; ah[3] = (_Float16)a0.w;
      ah[4] = (_Float16)a1.x; ah[5] = (_Float16)a1.y;
      ah[6] = (_Float16)a1.z; ah[7] = (_Float16)a1.w;
      #pragma unroll
      for (int nj = 0; nj < 7; nj++)
        acc[nj] = __builtin_amdgcn_mfma_f32_16x16x32_f16(ah, b[nj], acc[nj], 0, 0, 0);
      if (t < 23) {
        a0 = na0; a1 = na1;
        #pragma unroll
        for (int nj = 0; nj < 7; nj++) b[nj] = nb[nj];
      }
    }

    float uj[7], cj[7];
    #pragma unroll
    for (int nj = 0; nj < 7; nj++) { int j = nj*16 + lj; uj[nj] = u[j]; cj[nj] = csum[j]; }
    const float u100 = u[KCL];

    int idxr[4];
    #pragma unroll
    for (int r = 0; r < 4; r++) {
      // mu for row lk*4+r: col 100 -> nj=6, lj=4 lane of this group
      float mu = __shfl(acc[6][r], (lane & 48) + 4, 64) * SCINV + u100;
      float b1 = -3.4e38f, b2 = -3.4e38f; int i1 = 0;
      #pragma unroll
      for (int nj = 0; nj < 7; nj++) {
        int j = nj*16 + lj;
        float s = acc[nj][r] * SCINV + uj[nj] - mu * cj[nj];
        s = (j < KCL) ? s : -3.4e38f;
        if (s > b1) { b2 = b1; b1 = s; i1 = j; }
        else if (s > b2) { b2 = s; }
      }
      // reduce (best, idx, second) across the 16 lanes sharing these rows
      #pragma unroll
      for (int off = 1; off < 16; off <<= 1) {
        float ob1 = __shfl_xor(b1, off, 64);
        int   oi1 = __shfl_xor(i1, off, 64);
        float ob2 = __shfl_xor(b2, off, 64);
        if (ob1 > b1 || (ob1 == b1 && oi1 < i1)) {
          b2 = fmaxf(b1, fmaxf(b2, ob2)); b1 = ob1; i1 = oi1;
        } else {
          b2 = fmaxf(ob1, fmaxf(b2, ob2));
        }
      }
      idxr[r] = i1;
      if (lj == 0 && (b1 - b2) <= MARGIN) {   // near-tie: exact recompute in kC
        int p = atomicAdd(cnt, 1);
        list[p] = (unsigned short)(R + lk * 4 + r);
      }
    }

    // gather ZH[idx] -> out, 3 float4 per lane per row
    #pragma unroll
    for (int m = 0; m < 16; m++) {
      int idx = __shfl(idxr[m & 3], (m >> 2) << 4, 64);
      const float4* zs = (const float4*)(ZH + (size_t)idx * DIN);
      float4* od = (float4*)(out + (size_t)(R + m) * DIN);
      od[lane]       = zs[lane];
      od[lane + 64]  = zs[lane + 64];
      od[lane + 128] = zs[lane + 128];
    }
  } else {
    // ---- general (slow) path: ln_b != 0 -> full pat + LayerNorm. Correctness only. ----
    __shared__ float hrow2[DIN];
    __shared__ float patv[DCB];
    __shared__ float redf[2];
    __shared__ float Gsc[KCL];
    __shared__ int   sidx;
    const int r0 = blockIdx.x * 64;
    for (int rr = 0; rr < 64; rr++) {
      const size_t row = (size_t)(r0 + rr);
      __syncthreads();
      for (int d = tid; d < DIN; d += 256) hrow2[d] = hidden[row * DIN + d];
      __syncthreads();
      if (tid < DCB) {
        float a = b_low[tid];
        for (int d = 0; d < DIN; d++) a += hrow2[d] * W_low[(size_t)tid * DIN + d];
        patv[tid] = a;
      }
      __syncthreads();
      if (tid == 0) {
        float mu = 0.f; for (int c = 0; c < DCB; c++) mu += patv[c]; mu /= (float)DCB;
        float var = 0.f; for (int c = 0; c < DCB; c++) { float dd = patv[c] - mu; var += dd * dd; }
        var /= (float)DCB;
        redf[0] = mu; redf[1] = rsqrtf(var + 1e-5f);
      }
      __syncthreads();
      if (tid < DCB) patv[tid] = (patv[tid] - redf[0]) * redf[1];
      __syncthreads();
      if (tid < KCL) {
        float s = tv[tid];
        for (int c = 0; c < DCB; c++) s += patv[c] * S[(size_t)tid * DCB + c];
        Gsc[tid] = s;
      }
      __syncthreads();
      if (tid == 0) {
        float best = -3.4e38f; int bi = 0;
        for (int j = 0; j < KCL; j++) if (Gsc[j] > best) { best = Gsc[j]; bi = j; }
        sidx = bi;
      }
      __syncthreads();
      {
        int idx = sidx;
        for (int d4 = tid; d4 < DIN / 4; d4 += 256) {
          float4 v = *(const float4*)&ZH[(size_t)idx * DIN + d4 * 4];
          *(float4*)&out[row * DIN + d4 * 4] = v;
        }
      }
    }
  }
}

// ---------------- cleanup: exact (f64) rescore of near-tie rows ----------------
// pat_c = b_low_c + h.W_low[c,:] (f64); mu = mean(pat); s_j = sum_c (pat_c-mu)*S[j,c]
// identical to fast-path G+u-mu*csum identity, without needing an f32 Mt buffer.
__global__ void kC(const float* __restrict__ hidden, float* __restrict__ out,
                   const float* __restrict__ W_low, const float* __restrict__ b_low,
                   const float* __restrict__ S, const float* __restrict__ ZH,
                   const int* __restrict__ cnt, const unsigned short* __restrict__ list) {
  __shared__ float  hrow[DIN];
  __shared__ double pat[DCB];
  __shared__ double smu;
  __shared__ double sc[KCL];
  __shared__ int    bidx;
  const int n = *cnt;
  const int tid = threadIdx.x;
  for (int it = blockIdx.x; it < n; it += gridDim.x) {
    const int row = (int)list[it];
    __syncthreads();
    for (int d = tid; d < DIN; d += 256) hrow[d] = hidden[(size_t)row * DIN + d];
    __syncthreads();
    if (tid < DCB) {
      const float* wl = W_low + (size_t)tid * DIN;
      double a = (double)b_low[tid];
      for (int d = 0; d < DIN; d += 4) {
        a += (double)hrow[d]   * (double)wl[d]
           + (double)hrow[d+1] * (double)wl[d+1]
           + (double)hrow[d+2] * (double)wl[d+2]
           + (double)hrow[d+3] * (double)wl[d+3];
      }
      pat[tid] = a;
    }
    __syncthreads();
    if (tid == 0) {
      double m = 0.0;
      for (int c = 0; c < DCB; c++) m += pat[c];
      smu = m / (double)DCB;
    }
    __syncthreads();
    if (tid < KCL) {
      const float* sr = S + (size_t)tid * DCB;
      const double mu = smu;
      double a = 0.0;
      for (int c = 0; c < DCB; c++) a += (pat[c] - mu) * (double)sr[c];
      sc[tid] = a;
    }
    __syncthreads();
    if (tid == 0) {
      double best = -1e300; int bi = 0;
      for (int j = 0; j < KCL; j++)
        if (sc[j] > best) { best = sc[j]; bi = j; }   // strict >: first max on ties
      bidx = bi;
    }
    __syncthreads();
    {
      const int idx = bidx;
      for (int d4 = tid; d4 < DIN / 4; d4 += 256) {
        float4 v = *(const float4*)(ZH + (size_t)idx * DIN + d4 * 4);
        *(float4*)(out + (size_t)row * DIN + d4 * 4) = v;
      }
    }
  }
}

extern "C" void kernel_launch(void* const* d_in, const int* in_sizes, int n_in,
                              void* d_out, int out_size, void* d_ws, size_t ws_size,
                              hipStream_t stream) {
  const float* hidden = (const float*)d_in[0];
  const float* W_low  = (const float*)d_in[1];
  const float* b_low  = (const float*)d_in[2];
  const float* ln_g   = (const float*)d_in[3];
  const float* ln_b   = (const float*)d_in[4];
  const float* Wq     = (const float*)d_in[5];
  const float* Wk     = (const float*)d_in[6];
  // d_in[7] = Wv, d_in[8] = Wo: dead in forward (output == zq_h exactly)
  const float* cb     = (const float*)d_in[9];
  const float* W_high = (const float*)d_in[10];
  const float* b_high = (const float*)d_in[11];
  float* out = (float*)d_out;
  float* ws  = (float*)d_ws;

  float*          S    = ws + OFF_S;
  float*          csum = ws + OFF_CS;
  float*          u    = ws + OFF_U;
  float*          tv   = ws + OFF_T;
  float*          ZH   = ws + OFF_ZH;
  int*            flag = (int*)(ws + OFF_FLAG);
  int*            cnt  = (int*)(ws + OFF_CNT);
  _Float16*       Mth  = (_Float16*)(ws + OFF_MTH);
  float*          ktil = ws + OFF_KTIL;   // transient alias of Mth region
  unsigned short* list = (unsigned short*)(ws + OFF_LIST);

  kA1<<<KCL, DCB, 0, stream>>>(cb, Wk, ktil, flag, cnt);
  kA2<<<KCL, DCB, 0, stream>>>(Wq, ktil, ln_g, ln_b, b_low, S, csum, tv, u, flag);
  kA3<<<NJ,  256, 0, stream>>>(W_low, S, Mth);
  kA4<<<KCL, 256, 0, stream>>>(cb, W_high, b_high, ZH);
  kB<<<NB / 64, 256, 0, stream>>>(hidden, out, Mth, u, csum, ZH, flag, cnt, list,
                                  S, tv, W_low, b_low);
  kC<<<2048, 256, 0, stream>>>(hidden, out, W_low, b_low, S, ZH, cnt, list);
}

// Round 3
// 577.678 us; speedup vs baseline: 1.0971x; 1.0971x over previous
//
#include <hip/hip_runtime.h>

#define NB    65536   // batch rows
#define DIN   768     // hidden dim
#define DCB   192     // codebook hidden
#define KCL   100     // clusters
#define NJ    112     // padded j (100 scores + col100=mu + pad)

// workspace layout (float offsets) — total 172,116 floats = 688,464 B
#define OFF_S    0        // 100*192 f32 (persists: kB slow path + kC)
#define OFF_CS   19200    // 112
#define OFF_U    19312    // 112
#define OFF_T    19424    // 112
#define OFF_ZH   19536    // 100*768 f32
#define OFF_FLAG 96336    // 1 int
#define OFF_CNT  96337    // 1 int (flagged-row count)
#define OFF_MTH  96340    // 112*768 f16 = 43008 floats (byte 385360, 16B aligned)
#define OFF_KTIL 96340    // aliases Mth region: ktil dead before kA3 writes Mth
#define OFF_LIST 139348   // 65536 ushort row-ids = 32768 floats -> ends 172116

#define MARGIN 1e-4f      // ~14 sigma of f16-MFMA score error
#define MTSC   64.0f      // Mt pre-scale (argmax-invariant, keeps f16 normal-range)
#define SCINV  0.015625f

typedef __attribute__((ext_vector_type(8))) _Float16 half8;
typedef __attribute__((ext_vector_type(4))) float    f32x4;

// ---------------- setup kernels (small, f64 accumulation, coalesced) ----------------

__global__ void kA1(const float* __restrict__ cb, const float* __restrict__ Wk,
                    float* __restrict__ ktil, int* __restrict__ flag,
                    int* __restrict__ cnt) {
  __shared__ float cbrow[DCB];
  int j = blockIdx.x, i = threadIdx.x;  // block=192
  if (j == 0 && i == 0) { *flag = 0; *cnt = 0; }
  cbrow[i] = cb[j*DCB + i];
  __syncthreads();
  const float4* wr = (const float4*)&Wk[(size_t)i * DCB];
  double s0 = 0.0, s1 = 0.0;
  #pragma unroll 4
  for (int m4 = 0; m4 < DCB/4; m4++) {
    float4 w = wr[m4];
    s0 += (double)w.x * (double)cbrow[m4*4+0] + (double)w.z * (double)cbrow[m4*4+2];
    s1 += (double)w.y * (double)cbrow[m4*4+1] + (double)w.w * (double)cbrow[m4*4+3];
  }
  ktil[j*DCB+i] = (float)(s0 + s1);
}

__global__ void kA2(const float* __restrict__ Wq, const float* __restrict__ ktil,
                    const float* __restrict__ ln_g, const float* __restrict__ ln_b,
                    const float* __restrict__ b_low,
                    float* __restrict__ S, float* __restrict__ csum,
                    float* __restrict__ tv, float* __restrict__ u,
                    int* __restrict__ flag) {
  __shared__ float krow[DCB];
  __shared__ double red[DCB];
  int j = blockIdx.x, c = threadIdx.x;  // block=192
  krow[c] = ktil[j*DCB + c];
  __syncthreads();
  double a0 = 0.0, a1 = 0.0;
  #pragma unroll 4
  for (int i = 0; i < DCB; i += 2) {
    a0 += (double)Wq[i*DCB+c]     * (double)krow[i];
    a1 += (double)Wq[(i+1)*DCB+c] * (double)krow[i+1];
  }
  double a = a0 + a1;
  float Sv = ln_g[c] * (float)a;
  S[j*DCB+c] = Sv;

  red[c] = (double)Sv; __syncthreads();
  if (c == 0) {
    double p0=0,p1=0,p2=0,p3=0;
    for (int i = 0; i < DCB; i += 4) { p0+=red[i]; p1+=red[i+1]; p2+=red[i+2]; p3+=red[i+3]; }
    csum[j] = (float)(p0+p1+p2+p3);
  }
  __syncthreads();
  red[c] = (double)ln_b[c] * a; __syncthreads();
  if (c == 0) {
    double p0=0,p1=0,p2=0,p3=0;
    for (int i = 0; i < DCB; i += 4) { p0+=red[i]; p1+=red[i+1]; p2+=red[i+2]; p3+=red[i+3]; }
    float tf = (float)(p0+p1+p2+p3); tv[j] = tf;
    if (tf != 0.0f) atomicOr(flag, 1);
  }
  __syncthreads();
  red[c] = (double)b_low[c] * (double)Sv; __syncthreads();
  if (c == 0) {
    double p0=0,p1=0,p2=0,p3=0;
    for (int i = 0; i < DCB; i += 4) { p0+=red[i]; p1+=red[i+1]; p2+=red[i+2]; p3+=red[i+3]; }
    u[j] = (float)(p0+p1+p2+p3);
  }
  __syncthreads();
  if (j == 0) {
    red[c] = (double)b_low[c]; __syncthreads();
    if (c == 0) {
      double p0=0,p1=0,p2=0,p3=0;
      for (int i = 0; i < DCB; i += 4) { p0+=red[i]; p1+=red[i+1]; p2+=red[i+2]; p3+=red[i+3]; }
      u[KCL] = (float)((p0+p1+p2+p3) / (double)DCB);
      for (int p = KCL+1; p < NJ; p++) u[p] = 0.f;
      for (int p = KCL;   p < NJ; p++) { csum[p] = 0.f; tv[p] = 0.f; }
    }
  }
}

// Mth[j][d] = f16( MTSC * sum_c W_low[c,d]*S[j,c] ); row 100 = colmean; pads = 0
// grid = NJ*3 blocks x 256: one output element per thread
__global__ void kA3(const float* __restrict__ W_low, const float* __restrict__ S,
                    _Float16* __restrict__ Mth) {
  __shared__ float srow[DCB];
  int j = blockIdx.x / 3, st = blockIdx.x % 3;
  int t = threadIdx.x;
  int d = st * 256 + t;
  if (j < KCL && t < DCB) srow[t] = S[j*DCB + t];
  __syncthreads();
  float v;
  if (j < KCL) {
    double a = 0.0;
    for (int c = 0; c < DCB; c++) a += (double)W_low[(size_t)c*DIN + d] * (double)srow[c];
    v = (float)a;
  } else if (j == KCL) {
    double a = 0.0;
    for (int c = 0; c < DCB; c++) a += (double)W_low[(size_t)c*DIN + d];
    v = (float)(a / (double)DCB);
  } else {
    v = 0.f;
  }
  Mth[(size_t)j*DIN + d] = (_Float16)(v * MTSC);
}

__global__ void kA4(const float* __restrict__ cb, const float* __restrict__ W_high,
                    const float* __restrict__ b_high, float* __restrict__ ZH) {
  __shared__ float cbrow[DCB];
  int j = blockIdx.x, t = threadIdx.x;  // block=256
  if (t < DCB) cbrow[t] = cb[j*DCB + t];
  __syncthreads();
  #pragma unroll
  for (int kd = 0; kd < 3; kd++) {
    int d = t + 256*kd;
    const float4* wr = (const float4*)&W_high[(size_t)d * DCB];
    double s0 = 0.0, s1 = 0.0;
    #pragma unroll 4
    for (int c4 = 0; c4 < DCB/4; c4++) {
      float4 w = wr[c4];
      s0 += (double)w.x * (double)cbrow[c4*4+0] + (double)w.z * (double)cbrow[c4*4+2];
      s1 += (double)w.y * (double)cbrow[c4*4+1] + (double)w.w * (double)cbrow[c4*4+3];
    }
    ZH[(size_t)j*DIN + d] = (float)(s0 + s1 + (double)b_high[d]);
  }
}

// ---------------- main kernel: MFMA scores + LDS-staged B (swizzled) ----------------
// 512 blocks x 256 threads (4 waves). Block = 128 rows; wave = 32 rows (2 tiles of 16).
// B (Mth) staged per block in K-chunks of 128 (4 MFMA steps), double-buffered 2x28KB,
// XOR-swizzled (byte ^= (row&7)<<4) on write AND read -> conflict-free ds_read_b128.
// A: rolling 1-deep register prefetch from global (survives barrier: drain completes
// loads into live regs). Per-step VMEM = 4 A-loads only; B from ds pipe.
__global__ __launch_bounds__(256, 2)
void kB(const float* __restrict__ hidden, float* __restrict__ out,
        const _Float16* __restrict__ Mth, const float* __restrict__ u,
        const float* __restrict__ csum, const float* __restrict__ ZH,
        const int* __restrict__ flag, int* __restrict__ cnt,
        unsigned short* __restrict__ list,
        const float* __restrict__ S, const float* __restrict__ tv,
        const float* __restrict__ W_low, const float* __restrict__ b_low) {
  const int tid = threadIdx.x;
  __shared__ __align__(16) _Float16 Bs[2][14336];   // 2 x 28672 B
  if (*flag == 0) {
    const int lane = tid & 63;
    const int wv   = tid >> 6;
    const int lj   = lane & 15, lk = lane >> 4;
    const int R    = blockIdx.x * 128 + wv * 32;

    char* BsB = (char*)&Bs[0][0];

    // staging descriptors: 7 x uint4 per lane per chunk; linear source, swizzled dest
    const char* srcp[7]; int dstp[7];
    #pragma unroll
    for (int i = 0; i < 7; i++) {
      int o    = ((wv*7 + i)*64 + lane) * 16;  // byte offset in 28672B chunk
      int row  = o >> 8;
      int colb = o & 255;
      srcp[i] = (const char*)Mth + row*1536 + colb;          // +kc*256 per chunk
      dstp[i] = row*256 + (colb ^ ((row & 7) << 4));         // swizzled LDS byte
    }

    const float* A0 = hidden + (size_t)(R + lj) * DIN + lk * 8;
    const float* A1 = A0 + 16 * DIN;

    f32x4 acc[2][7];
    #pragma unroll
    for (int m = 0; m < 2; m++)
      #pragma unroll
      for (int nj = 0; nj < 7; nj++) acc[m][nj] = (f32x4){0.f, 0.f, 0.f, 0.f};

    // prologue: stage chunk 0, preload A step 0
    uint4 stg[7];
    #pragma unroll
    for (int i = 0; i < 7; i++) stg[i] = *(const uint4*)(srcp[i]);
    float4 Ac[2][2];
    Ac[0][0] = *(const float4*)(A0); Ac[0][1] = *(const float4*)(A0 + 4);
    Ac[1][0] = *(const float4*)(A1); Ac[1][1] = *(const float4*)(A1 + 4);
    #pragma unroll
    for (int i = 0; i < 7; i++) *(uint4*)(BsB + dstp[i]) = stg[i];
    __syncthreads();

    for (int kc = 0; kc < 6; kc++) {
      const int cur = kc & 1;
      if (kc < 5) {                          // issue next-chunk B loads early (T14)
        #pragma unroll
        for (int i = 0; i < 7; i++)
          stg[i] = *(const uint4*)(srcp[i] + (kc + 1) * 256);
      }
      #pragma unroll
      for (int s = 0; s < 4; s++) {
        const int g = kc*4 + s;
        float4 An[2][2];
        if (g < 23) {                        // rolling A prefetch, 1 step deep
          const float* p0 = A0 + (g + 1) * 32;
          const float* p1 = A1 + (g + 1) * 32;
          An[0][0] = *(const float4*)(p0); An[0][1] = *(const float4*)(p0 + 4);
          An[1][0] = *(const float4*)(p1); An[1][1] = *(const float4*)(p1 + 4);
        }
        half8 bfr[7];
        const char* bbase = BsB + cur * 28672;
        #pragma unroll
        for (int nj = 0; nj < 7; nj++) {
          int row = nj*16 + lj;
          int off = row*256 + ((lk*16 + s*64) ^ ((row & 7) << 4));
          bfr[nj] = *(const half8*)(bbase + off);
        }
        #pragma unroll
        for (int m = 0; m < 2; m++) {
          half8 ah;
          ah[0] = (_Float16)Ac[m][0].x; ah[1] = (_Float16)Ac[m][0].y;
          ah[2] = (_Float16)Ac[m][0].z; ah[3] = (_Float16)Ac[m][0].w;
          ah[4] = (_Float16)Ac[m][1].x; ah[5] = (_Float16)Ac[m][1].y;
          ah[6] = (_Float16)Ac[m][1].z; ah[7] = (_Float16)Ac[m][1].w;
          #pragma unroll
          for (int nj = 0; nj < 7; nj++)
            acc[m][nj] = __builtin_amdgcn_mfma_f32_16x16x32_f16(ah, bfr[nj], acc[m][nj], 0, 0, 0);
        }
        if (g < 23) {
          Ac[0][0] = An[0][0]; Ac[0][1] = An[0][1];
          Ac[1][0] = An[1][0]; Ac[1][1] = An[1][1];
        }
      }
      if (kc < 5) {                          // write-late into the other buffer
        #pragma unroll
        for (int i = 0; i < 7; i++)
          *(uint4*)(BsB + (cur ^ 1) * 28672 + dstp[i]) = stg[i];
      }
      __syncthreads();
    }

    float uj[7], cj[7];
    #pragma unroll
    for (int nj = 0; nj < 7; nj++) { int j = nj*16 + lj; uj[nj] = u[j]; cj[nj] = csum[j]; }
    const float u100 = u[KCL];

    int idxr[2][4];
    #pragma unroll
    for (int m = 0; m < 2; m++) {
      #pragma unroll
      for (int r = 0; r < 4; r++) {
        // mu for row m*16 + lk*4 + r: col 100 -> nj=6, lj=4 lane of this group
        float mu = __shfl(acc[m][6][r], (lane & 48) + 4, 64) * SCINV + u100;
        float b1 = -3.4e38f, b2 = -3.4e38f; int i1 = 0;
        #pragma unroll
        for (int nj = 0; nj < 7; nj++) {
          int j = nj*16 + lj;
          float sv = acc[m][nj][r] * SCINV + uj[nj] - mu * cj[nj];
          sv = (j < KCL) ? sv : -3.4e38f;
          if (sv > b1) { b2 = b1; b1 = sv; i1 = j; }
          else if (sv > b2) { b2 = sv; }
        }
        #pragma unroll
        for (int off = 1; off < 16; off <<= 1) {
          float ob1 = __shfl_xor(b1, off, 64);
          int   oi1 = __shfl_xor(i1, off, 64);
          float ob2 = __shfl_xor(b2, off, 64);
          if (ob1 > b1 || (ob1 == b1 && oi1 < i1)) {
            b2 = fmaxf(b1, fmaxf(b2, ob2)); b1 = ob1; i1 = oi1;
          } else {
            b2 = fmaxf(ob1, fmaxf(b2, ob2));
          }
        }
        idxr[m][r] = i1;
        if (lj == 0 && (b1 - b2) <= MARGIN) {   // near-tie: exact recompute in kC
          int p = atomicAdd(cnt, 1);
          list[p] = (unsigned short)(R + m*16 + lk*4 + r);
        }
      }
    }

    // gather ZH[idx] -> out, 3 float4 per lane per row
    #pragma unroll
    for (int rr = 0; rr < 32; rr++) {
      int idx = __shfl(idxr[rr >> 4][rr & 3], ((rr & 15) >> 2) << 4, 64);
      const float4* zs = (const float4*)(ZH + (size_t)idx * DIN);
      float4* od = (float4*)(out + (size_t)(R + rr) * DIN);
      od[lane]       = zs[lane];
      od[lane + 64]  = zs[lane + 64];
      od[lane + 128] = zs[lane + 128];
    }
  } else {
    // ---- general (slow) path: ln_b != 0 -> full pat + LayerNorm. Correctness only. ----
    __shared__ float hrow2[DIN];
    __shared__ float patv[DCB];
    __shared__ float redf[2];
    __shared__ float Gsc[KCL];
    __shared__ int   sidx;
    const int r0 = blockIdx.x * 128;
    for (int rr = 0; rr < 128; rr++) {
      const size_t row = (size_t)(r0 + rr);
      __syncthreads();
      for (int d = tid; d < DIN; d += 256) hrow2[d] = hidden[row * DIN + d];
      __syncthreads();
      if (tid < DCB) {
        float a = b_low[tid];
        for (int d = 0; d < DIN; d++) a += hrow2[d] * W_low[(size_t)tid * DIN + d];
        patv[tid] = a;
      }
      __syncthreads();
      if (tid == 0) {
        float mu = 0.f; for (int c = 0; c < DCB; c++) mu += patv[c]; mu /= (float)DCB;
        float var = 0.f; for (int c = 0; c < DCB; c++) { float dd = patv[c] - mu; var += dd * dd; }
        var /= (float)DCB;
        redf[0] = mu; redf[1] = rsqrtf(var + 1e-5f);
      }
      __syncthreads();
      if (tid < DCB) patv[tid] = (patv[tid] - redf[0]) * redf[1];
      __syncthreads();
      if (tid < KCL) {
        float s = tv[tid];
        for (int c = 0; c < DCB; c++) s += patv[c] * S[(size_t)tid * DCB + c];
        Gsc[tid] = s;
      }
      __syncthreads();
      if (tid == 0) {
        float best = -3.4e38f; int bi = 0;
        for (int j = 0; j < KCL; j++) if (Gsc[j] > best) { best = Gsc[j]; bi = j; }
        sidx = bi;
      }
      __syncthreads();
      {
        int idx = sidx;
        for (int d4 = tid; d4 < DIN / 4; d4 += 256) {
          float4 v = *(const float4*)&ZH[(size_t)idx * DIN + d4 * 4];
          *(float4*)&out[row * DIN + d4 * 4] = v;
        }
      }
    }
  }
}

// ---------------- cleanup: exact (f64) rescore of near-tie rows ----------------
__global__ void kC(const float* __restrict__ hidden, float* __restrict__ out,
                   const float* __restrict__ W_low, const float* __restrict__ b_low,
                   const float* __restrict__ S, const float* __restrict__ ZH,
                   const int* __restrict__ cnt, const unsigned short* __restrict__ list) {
  __shared__ float  hrow[DIN];
  __shared__ double pat[DCB];
  __shared__ double smu;
  __shared__ double sc[KCL];
  __shared__ int    bidx;
  const int n = *cnt;
  const int tid = threadIdx.x;
  for (int it = blockIdx.x; it < n; it += gridDim.x) {
    const int row = (int)list[it];
    __syncthreads();
    for (int d = tid; d < DIN; d += 256) hrow[d] = hidden[(size_t)row * DIN + d];
    __syncthreads();
    if (tid < DCB) {
      const float* wl = W_low + (size_t)tid * DIN;
      double a = (double)b_low[tid];
      for (int d = 0; d < DIN; d += 4) {
        a += (double)hrow[d]   * (double)wl[d]
           + (double)hrow[d+1] * (double)wl[d+1]
           + (double)hrow[d+2] * (double)wl[d+2]
           + (double)hrow[d+3] * (double)wl[d+3];
      }
      pat[tid] = a;
    }
    __syncthreads();
    if (tid == 0) {
      double m = 0.0;
      for (int c = 0; c < DCB; c++) m += pat[c];
      smu = m / (double)DCB;
    }
    __syncthreads();
    if (tid < KCL) {
      const float* sr = S + (size_t)tid * DCB;
      const double mu = smu;
      double a = 0.0;
      for (int c = 0; c < DCB; c++) a += (pat[c] - mu) * (double)sr[c];
      sc[tid] = a;
    }
    __syncthreads();
    if (tid == 0) {
      double best = -1e300; int bi = 0;
      for (int j = 0; j < KCL; j++)
        if (sc[j] > best) { best = sc[j]; bi = j; }   // strict >: first max on ties
      bidx = bi;
    }
    __syncthreads();
    {
      const int idx = bidx;
      for (int d4 = tid; d4 < DIN / 4; d4 += 256) {
        float4 v = *(const float4*)(ZH + (size_t)idx * DIN + d4 * 4);
        *(float4*)(out + (size_t)row * DIN + d4 * 4) = v;
      }
    }
  }
}

extern "C" void kernel_launch(void* const* d_in, const int* in_sizes, int n_in,
                              void* d_out, int out_size, void* d_ws, size_t ws_size,
                              hipStream_t stream) {
  const float* hidden = (const float*)d_in[0];
  const float* W_low  = (const float*)d_in[1];
  const float* b_low  = (const float*)d_in[2];
  const float* ln_g   = (const float*)d_in[3];
  const float* ln_b   = (const float*)d_in[4];
  const float* Wq     = (const float*)d_in[5];
  const float* Wk     = (const float*)d_in[6];
  // d_in[7] = Wv, d_in[8] = Wo: dead in forward (output == zq_h exactly)
  const float* cb     = (const float*)d_in[9];
  const float* W_high = (const float*)d_in[10];
  const float* b_high = (const float*)d_in[11];
  float* out = (float*)d_out;
  float* ws  = (float*)d_ws;

  float*          S    = ws + OFF_S;
  float*          csum = ws + OFF_CS;
  float*          u    = ws + OFF_U;
  float*          tv   = ws + OFF_T;
  float*          ZH   = ws + OFF_ZH;
  int*            flag = (int*)(ws + OFF_FLAG);
  int*            cnt  = (int*)(ws + OFF_CNT);
  _Float16*       Mth  = (_Float16*)(ws + OFF_MTH);
  float*          ktil = ws + OFF_KTIL;   // transient alias of Mth region
  unsigned short* list = (unsigned short*)(ws + OFF_LIST);

  kA1<<<KCL, DCB, 0, stream>>>(cb, Wk, ktil, flag, cnt);
  kA2<<<KCL, DCB, 0, stream>>>(Wq, ktil, ln_g, ln_b, b_low, S, csum, tv, u, flag);
  kA3<<<NJ*3, 256, 0, stream>>>(W_low, S, Mth);
  kA4<<<KCL, 256, 0, stream>>>(cb, W_high, b_high, ZH);
  kB<<<NB / 128, 256, 0, stream>>>(hidden, out, Mth, u, csum, ZH, flag, cnt, list,
                                   S, tv, W_low, b_low);
  kC<<<2048, 256, 0, stream>>>(hidden, out, W_low, b_low, S, ZH, cnt, list);
}

// Round 5
// 506.994 us; speedup vs baseline: 1.2500x; 1.1394x over previous
//
#include <hip/hip_runtime.h>

#define NB    65536   // batch rows
#define DIN   768     // hidden dim
#define DCB   192     // codebook hidden
#define KCL   100     // clusters
#define NJ    112     // padded j (100 scores + col100=mu + pad)

// workspace layout (float offsets) — total 172,116 floats = 688,464 B (proven r3)
#define OFF_S    0        // 100*192 f32 (persists: kB slow path + kC)
#define OFF_CS   19200    // 112
#define OFF_U    19312    // 112
#define OFF_T    19424    // 112
#define OFF_ZH   19536    // 100*768 f32
#define OFF_FLAG 96336    // 1 int
#define OFF_CNT  96337    // 1 int (flagged-row count)
#define OFF_MTH  96340    // 112*768 f16 = 43008 floats (byte 385360, 16B aligned)
#define OFF_LIST 139348   // 65536 ushort row-ids = 32768 floats -> ends 172116

#define MARGIN 1e-4f      // ~10 sigma of f16-MFMA score error
#define MTSC   64.0f      // Mt pre-scale (argmax-invariant, keeps f16 normal-range)
#define SCINV  0.015625f

typedef __attribute__((ext_vector_type(8))) _Float16 half8;
typedef __attribute__((ext_vector_type(4))) float    f32x4;

// ---------------- fused setup kernel ----------------
// grid = NJ + KCL = 212 blocks x 256 threads.
// Blocks [0,NJ): per-j chain ktil(LDS) -> S row j -> csum/tv/u -> Mth row j (f16*MTSC).
// Blocks [NJ,NJ+KCL): ZH row (j-NJ).
// flag/cnt are zeroed by a hipMemsetAsync BEFORE this kernel (no init/atomicOr race).
__global__ void kA(const float* __restrict__ cb, const float* __restrict__ Wk,
                   const float* __restrict__ Wq, const float* __restrict__ ln_g,
                   const float* __restrict__ ln_b, const float* __restrict__ b_low,
                   const float* __restrict__ W_low, const float* __restrict__ W_high,
                   const float* __restrict__ b_high,
                   float* __restrict__ S, float* __restrict__ csum,
                   float* __restrict__ tv, float* __restrict__ u,
                   _Float16* __restrict__ Mth, float* __restrict__ ZH,
                   int* __restrict__ flag) {
  const int bj = blockIdx.x;
  const int t  = threadIdx.x;   // 256
  if (bj < NJ) {
    __shared__ float  cbrow[DCB];
    __shared__ float  krow[DCB];
    __shared__ float  srow[DCB];
    __shared__ double red[DCB];
    const int j = bj;
    if (j < KCL) {
      // stage 1: ktil row j (f32 in LDS, f64 accumulation — identical to kA1)
      if (t < DCB) cbrow[t] = cb[j*DCB + t];
      __syncthreads();
      if (t < DCB) {
        const float4* wr = (const float4*)&Wk[(size_t)t * DCB];
        double s0 = 0.0, s1 = 0.0;
        #pragma unroll 4
        for (int m4 = 0; m4 < DCB/4; m4++) {
          float4 w = wr[m4];
          s0 += (double)w.x * (double)cbrow[m4*4+0] + (double)w.z * (double)cbrow[m4*4+2];
          s1 += (double)w.y * (double)cbrow[m4*4+1] + (double)w.w * (double)cbrow[m4*4+3];
        }
        krow[t] = (float)(s0 + s1);
      }
      __syncthreads();
      // stage 2: S row j + reductions (identical numerics to kA2)
      double a = 0.0;
      if (t < DCB) {
        double a0 = 0.0, a1 = 0.0;
        #pragma unroll 4
        for (int i = 0; i < DCB; i += 2) {
          a0 += (double)Wq[i*DCB+t]     * (double)krow[i];
          a1 += (double)Wq[(i+1)*DCB+t] * (double)krow[i+1];
        }
        a = a0 + a1;
        float Sv = ln_g[t] * (float)a;
        srow[t] = Sv;
        S[j*DCB + t] = Sv;
      }
      __syncthreads();
      if (t < DCB) red[t] = (double)srow[t];
      __syncthreads();
      if (t == 0) {
        double p0=0,p1=0,p2=0,p3=0;
        for (int i = 0; i < DCB; i += 4) { p0+=red[i]; p1+=red[i+1]; p2+=red[i+2]; p3+=red[i+3]; }
        csum[j] = (float)(p0+p1+p2+p3);
      }
      __syncthreads();
      if (t < DCB) red[t] = (double)ln_b[t] * a;
      __syncthreads();
      if (t == 0) {
        double p0=0,p1=0,p2=0,p3=0;
        for (int i = 0; i < DCB; i += 4) { p0+=red[i]; p1+=red[i+1]; p2+=red[i+2]; p3+=red[i+3]; }
        float tf = (float)(p0+p1+p2+p3); tv[j] = tf;
        if (tf != 0.0f) atomicOr(flag, 1);
      }
      __syncthreads();
      if (t < DCB) red[t] = (double)b_low[t] * (double)srow[t];
      __syncthreads();
      if (t == 0) {
        double p0=0,p1=0,p2=0,p3=0;
        for (int i = 0; i < DCB; i += 4) { p0+=red[i]; p1+=red[i+1]; p2+=red[i+2]; p3+=red[i+3]; }
        u[j] = (float)(p0+p1+p2+p3);
      }
      __syncthreads();
      if (j == 0) {
        if (t < DCB) red[t] = (double)b_low[t];
        __syncthreads();
        if (t == 0) {
          double p0=0,p1=0,p2=0,p3=0;
          for (int i = 0; i < DCB; i += 4) { p0+=red[i]; p1+=red[i+1]; p2+=red[i+2]; p3+=red[i+3]; }
          u[KCL] = (float)((p0+p1+p2+p3) / (double)DCB);
          for (int p = KCL+1; p < NJ; p++) u[p] = 0.f;
          for (int p = KCL;   p < NJ; p++) { csum[p] = 0.f; tv[p] = 0.f; }
        }
        __syncthreads();
      }
      // stage 3: Mth row j (identical numerics to kA3)
      #pragma unroll
      for (int kd = 0; kd < 3; kd++) {
        int d = t + 256*kd;
        double a3 = 0.0;
        for (int c = 0; c < DCB; c++)
          a3 += (double)W_low[(size_t)c*DIN + d] * (double)srow[c];
        Mth[(size_t)j*DIN + d] = (_Float16)(((float)a3) * MTSC);
      }
    } else if (j == KCL) {
      #pragma unroll
      for (int kd = 0; kd < 3; kd++) {
        int d = t + 256*kd;
        double a3 = 0.0;
        for (int c = 0; c < DCB; c++) a3 += (double)W_low[(size_t)c*DIN + d];
        Mth[(size_t)j*DIN + d] = (_Float16)(((float)(a3 / (double)DCB)) * MTSC);
      }
    } else {
      #pragma unroll
      for (int kd = 0; kd < 3; kd++) {
        int d = t + 256*kd;
        Mth[(size_t)j*DIN + d] = (_Float16)0.f;
      }
    }
  } else {
    // ZH row j2 (identical numerics to kA4)
    __shared__ float cbr2[DCB];
    const int j2 = bj - NJ;
    if (t < DCB) cbr2[t] = cb[j2*DCB + t];
    __syncthreads();
    #pragma unroll
    for (int kd = 0; kd < 3; kd++) {
      int d = t + 256*kd;
      const float4* wr = (const float4*)&W_high[(size_t)d * DCB];
      double s0 = 0.0, s1 = 0.0;
      #pragma unroll 4
      for (int c4 = 0; c4 < DCB/4; c4++) {
        float4 w = wr[c4];
        s0 += (double)w.x * (double)cbr2[c4*4+0] + (double)w.z * (double)cbr2[c4*4+2];
        s1 += (double)w.y * (double)cbr2[c4*4+1] + (double)w.w * (double)cbr2[c4*4+3];
      }
      ZH[(size_t)j2*DIN + d] = (float)(s0 + s1 + (double)b_high[d]);
    }
  }
}

// ---------------- main kernel: MFMA scores + LDS-staged B (swizzled) ----------------
// VERBATIM round-3 kernel (proven 145us): 512 blocks x 256 threads (4 waves).
// Block = 128 rows; wave = 32 rows (2 tiles of 16). B staged per K-chunk of 128,
// double-buffered 2x28KB, XOR-swizzled (byte ^= (row&7)<<4) write+read.
__global__ __launch_bounds__(256, 2)
void kB(const float* __restrict__ hidden, float* __restrict__ out,
        const _Float16* __restrict__ Mth, const float* __restrict__ u,
        const float* __restrict__ csum, const float* __restrict__ ZH,
        const int* __restrict__ flag, int* __restrict__ cnt,
        unsigned short* __restrict__ list,
        const float* __restrict__ S, const float* __restrict__ tv,
        const float* __restrict__ W_low, const float* __restrict__ b_low) {
  const int tid = threadIdx.x;
  __shared__ __align__(16) _Float16 Bs[2][14336];   // 2 x 28672 B
  if (*flag == 0) {
    const int lane = tid & 63;
    const int wv   = tid >> 6;
    const int lj   = lane & 15, lk = lane >> 4;
    const int R    = blockIdx.x * 128 + wv * 32;

    char* BsB = (char*)&Bs[0][0];

    const char* srcp[7]; int dstp[7];
    #pragma unroll
    for (int i = 0; i < 7; i++) {
      int o    = ((wv*7 + i)*64 + lane) * 16;  // byte offset in 28672B chunk
      int row  = o >> 8;
      int colb = o & 255;
      srcp[i] = (const char*)Mth + row*1536 + colb;          // +kc*256 per chunk
      dstp[i] = row*256 + (colb ^ ((row & 7) << 4));         // swizzled LDS byte
    }

    const float* A0 = hidden + (size_t)(R + lj) * DIN + lk * 8;
    const float* A1 = A0 + 16 * DIN;

    f32x4 acc[2][7];
    #pragma unroll
    for (int m = 0; m < 2; m++)
      #pragma unroll
      for (int nj = 0; nj < 7; nj++) acc[m][nj] = (f32x4){0.f, 0.f, 0.f, 0.f};

    uint4 stg[7];
    #pragma unroll
    for (int i = 0; i < 7; i++) stg[i] = *(const uint4*)(srcp[i]);
    float4 Ac[2][2];
    Ac[0][0] = *(const float4*)(A0); Ac[0][1] = *(const float4*)(A0 + 4);
    Ac[1][0] = *(const float4*)(A1); Ac[1][1] = *(const float4*)(A1 + 4);
    #pragma unroll
    for (int i = 0; i < 7; i++) *(uint4*)(BsB + dstp[i]) = stg[i];
    __syncthreads();

    for (int kc = 0; kc < 6; kc++) {
      const int cur = kc & 1;
      if (kc < 5) {
        #pragma unroll
        for (int i = 0; i < 7; i++)
          stg[i] = *(const uint4*)(srcp[i] + (kc + 1) * 256);
      }
      #pragma unroll
      for (int s = 0; s < 4; s++) {
        const int g = kc*4 + s;
        float4 An[2][2];
        if (g < 23) {
          const float* p0 = A0 + (g + 1) * 32;
          const float* p1 = A1 + (g + 1) * 32;
          An[0][0] = *(const float4*)(p0); An[0][1] = *(const float4*)(p0 + 4);
          An[1][0] = *(const float4*)(p1); An[1][1] = *(const float4*)(p1 + 4);
        }
        half8 bfr[7];
        const char* bbase = BsB + cur * 28672;
        #pragma unroll
        for (int nj = 0; nj < 7; nj++) {
          int row = nj*16 + lj;
          int off = row*256 + ((lk*16 + s*64) ^ ((row & 7) << 4));
          bfr[nj] = *(const half8*)(bbase + off);
        }
        #pragma unroll
        for (int m = 0; m < 2; m++) {
          half8 ah;
          ah[0] = (_Float16)Ac[m][0].x; ah[1] = (_Float16)Ac[m][0].y;
          ah[2] = (_Float16)Ac[m][0].z; ah[3] = (_Float16)Ac[m][0].w;
          ah[4] = (_Float16)Ac[m][1].x; ah[5] = (_Float16)Ac[m][1].y;
          ah[6] = (_Float16)Ac[m][1].z; ah[7] = (_Float16)Ac[m][1].w;
          #pragma unroll
          for (int nj = 0; nj < 7; nj++)
            acc[m][nj] = __builtin_amdgcn_mfma_f32_16x16x32_f16(ah, bfr[nj], acc[m][nj], 0, 0, 0);
        }
        if (g < 23) {
          Ac[0][0] = An[0][0]; Ac[0][1] = An[0][1];
          Ac[1][0] = An[1][0]; Ac[1][1] = An[1][1];
        }
      }
      if (kc < 5) {
        #pragma unroll
        for (int i = 0; i < 7; i++)
          *(uint4*)(BsB + (cur ^ 1) * 28672 + dstp[i]) = stg[i];
      }
      __syncthreads();
    }

    float uj[7], cj[7];
    #pragma unroll
    for (int nj = 0; nj < 7; nj++) { int j = nj*16 + lj; uj[nj] = u[j]; cj[nj] = csum[j]; }
    const float u100 = u[KCL];

    int idxr[2][4];
    #pragma unroll
    for (int m = 0; m < 2; m++) {
      #pragma unroll
      for (int r = 0; r < 4; r++) {
        float mu = __shfl(acc[m][6][r], (lane & 48) + 4, 64) * SCINV + u100;
        float b1 = -3.4e38f, b2 = -3.4e38f; int i1 = 0;
        #pragma unroll
        for (int nj = 0; nj < 7; nj++) {
          int j = nj*16 + lj;
          float sv = acc[m][nj][r] * SCINV + uj[nj] - mu * cj[nj];
          sv = (j < KCL) ? sv : -3.4e38f;
          if (sv > b1) { b2 = b1; b1 = sv; i1 = j; }
          else if (sv > b2) { b2 = sv; }
        }
        #pragma unroll
        for (int off = 1; off < 16; off <<= 1) {
          float ob1 = __shfl_xor(b1, off, 64);
          int   oi1 = __shfl_xor(i1, off, 64);
          float ob2 = __shfl_xor(b2, off, 64);
          if (ob1 > b1 || (ob1 == b1 && oi1 < i1)) {
            b2 = fmaxf(b1, fmaxf(b2, ob2)); b1 = ob1; i1 = oi1;
          } else {
            b2 = fmaxf(ob1, fmaxf(b2, ob2));
          }
        }
        idxr[m][r] = i1;
        if (lj == 0 && (b1 - b2) <= MARGIN) {
          int p = atomicAdd(cnt, 1);
          list[p] = (unsigned short)(R + m*16 + lk*4 + r);
        }
      }
    }

    #pragma unroll
    for (int rr = 0; rr < 32; rr++) {
      int idx = __shfl(idxr[rr >> 4][rr & 3], ((rr & 15) >> 2) << 4, 64);
      const float4* zs = (const float4*)(ZH + (size_t)idx * DIN);
      float4* od = (float4*)(out + (size_t)(R + rr) * DIN);
      od[lane]       = zs[lane];
      od[lane + 64]  = zs[lane + 64];
      od[lane + 128] = zs[lane + 128];
    }
  } else {
    // ---- general (slow) path: ln_b != 0 -> full pat + LayerNorm. Correctness only. ----
    __shared__ float hrow2[DIN];
    __shared__ float patv[DCB];
    __shared__ float redf[2];
    __shared__ float Gsc[KCL];
    __shared__ int   sidx;
    const int r0 = blockIdx.x * 128;
    for (int rr = 0; rr < 128; rr++) {
      const size_t row = (size_t)(r0 + rr);
      __syncthreads();
      for (int d = tid; d < DIN; d += 256) hrow2[d] = hidden[row * DIN + d];
      __syncthreads();
      if (tid < DCB) {
        float a = b_low[tid];
        for (int d = 0; d < DIN; d++) a += hrow2[d] * W_low[(size_t)tid * DIN + d];
        patv[tid] = a;
      }
      __syncthreads();
      if (tid == 0) {
        float mu = 0.f; for (int c = 0; c < DCB; c++) mu += patv[c]; mu /= (float)DCB;
        float var = 0.f; for (int c = 0; c < DCB; c++) { float dd = patv[c] - mu; var += dd * dd; }
        var /= (float)DCB;
        redf[0] = mu; redf[1] = rsqrtf(var + 1e-5f);
      }
      __syncthreads();
      if (tid < DCB) patv[tid] = (patv[tid] - redf[0]) * redf[1];
      __syncthreads();
      if (tid < KCL) {
        float s = tv[tid];
        for (int c = 0; c < DCB; c++) s += patv[c] * S[(size_t)tid * DCB + c];
        Gsc[tid] = s;
      }
      __syncthreads();
      if (tid == 0) {
        float best = -3.4e38f; int bi = 0;
        for (int j = 0; j < KCL; j++) if (Gsc[j] > best) { best = Gsc[j]; bi = j; }
        sidx = bi;
      }
      __syncthreads();
      {
        int idx = sidx;
        for (int d4 = tid; d4 < DIN / 4; d4 += 256) {
          float4 v = *(const float4*)&ZH[(size_t)idx * DIN + d4 * 4];
          *(float4*)&out[row * DIN + d4 * 4] = v;
        }
      }
    }
  }
}

// ---------------- cleanup: exact (f64) rescore, 8 rows per W_low sweep ----------------
__global__ __launch_bounds__(256)
void kC(const float* __restrict__ hidden, float* __restrict__ out,
        const float* __restrict__ W_low, const float* __restrict__ b_low,
        const float* __restrict__ S, const float* __restrict__ ZH,
        const int* __restrict__ cnt, const unsigned short* __restrict__ list) {
  __shared__ float  hrow[8][DIN];    // 24,576 B
  __shared__ double pat[8][DCB];     // 12,288 B
  __shared__ double mu8[8];
  __shared__ double sc[KCL][8];      //  6,400 B
  __shared__ int    bidx[8];
  const int tid = threadIdx.x;
  int n = *cnt; if (n > NB) n = NB;
  const int nb = (n + 7) >> 3;
  for (int bt = blockIdx.x; bt < nb; bt += gridDim.x) {
    const int base = bt * 8;
    const int cr = (n - base < 8) ? (n - base) : 8;
    __syncthreads();                 // protect LDS reuse across grid-stride iterations
    for (int f = tid; f < cr * 192; f += 256) {
      int r = f / 192, d4 = f - r * 192;
      ((float4*)&hrow[r][0])[d4] =
        *(const float4*)&hidden[(size_t)list[base + r] * DIN + d4 * 4];
    }
    __syncthreads();
    if (tid < DCB) {
      const float4* wl = (const float4*)&W_low[(size_t)tid * DIN];
      double a[8];
      #pragma unroll
      for (int r = 0; r < 8; r++) a[r] = (double)b_low[tid];
      for (int d4 = 0; d4 < DIN/4; d4++) {
        float4 w = wl[d4];
        #pragma unroll
        for (int r = 0; r < 8; r++) {
          a[r] += (double)hrow[r][d4*4+0] * (double)w.x
                + (double)hrow[r][d4*4+1] * (double)w.y
                + (double)hrow[r][d4*4+2] * (double)w.z
                + (double)hrow[r][d4*4+3] * (double)w.w;
        }
      }
      #pragma unroll
      for (int r = 0; r < 8; r++) pat[r][tid] = a[r];
    }
    __syncthreads();
    if (tid < 8) {
      double m = 0.0;
      for (int c = 0; c < DCB; c++) m += pat[tid][c];
      mu8[tid] = m / (double)DCB;
    }
    __syncthreads();
    if (tid < KCL) {
      const float* sr = S + (size_t)tid * DCB;
      double a[8];
      #pragma unroll
      for (int r = 0; r < 8; r++) a[r] = 0.0;
      for (int c = 0; c < DCB; c++) {
        double sv = (double)sr[c];
        #pragma unroll
        for (int r = 0; r < 8; r++) a[r] += (pat[r][c] - mu8[r]) * sv;
      }
      #pragma unroll
      for (int r = 0; r < 8; r++) sc[tid][r] = a[r];
    }
    __syncthreads();
    if (tid < cr) {
      double best = -1e300; int bi = 0;
      for (int jj = 0; jj < KCL; jj++)
        if (sc[jj][tid] > best) { best = sc[jj][tid]; bi = jj; }  // strict >: first max
      bidx[tid] = bi;
    }
    __syncthreads();
    for (int f = tid; f < cr * 192; f += 256) {
      int r = f / 192, d4 = f - r * 192;
      float4 v = ((const float4*)&ZH[(size_t)bidx[r] * DIN])[d4];
      ((float4*)&out[(size_t)list[base + r] * DIN])[d4] = v;
    }
  }
}

extern "C" void kernel_launch(void* const* d_in, const int* in_sizes, int n_in,
                              void* d_out, int out_size, void* d_ws, size_t ws_size,
                              hipStream_t stream) {
  const float* hidden = (const float*)d_in[0];
  const float* W_low  = (const float*)d_in[1];
  const float* b_low  = (const float*)d_in[2];
  const float* ln_g   = (const float*)d_in[3];
  const float* ln_b   = (const float*)d_in[4];
  const float* Wq     = (const float*)d_in[5];
  const float* Wk     = (const float*)d_in[6];
  // d_in[7] = Wv, d_in[8] = Wo: dead in forward (output == zq_h exactly)
  const float* cb     = (const float*)d_in[9];
  const float* W_high = (const float*)d_in[10];
  const float* b_high = (const float*)d_in[11];
  float* out = (float*)d_out;
  float* ws  = (float*)d_ws;

  float*          S    = ws + OFF_S;
  float*          csum = ws + OFF_CS;
  float*          u    = ws + OFF_U;
  float*          tv   = ws + OFF_T;
  float*          ZH   = ws + OFF_ZH;
  int*            flag = (int*)(ws + OFF_FLAG);
  int*            cnt  = (int*)(ws + OFF_CNT);
  _Float16*       Mth  = (_Float16*)(ws + OFF_MTH);
  unsigned short* list = (unsigned short*)(ws + OFF_LIST);

  hipMemsetAsync((void*)flag, 0, 8, stream);   // flag + cnt
  kA<<<NJ + KCL, 256, 0, stream>>>(cb, Wk, Wq, ln_g, ln_b, b_low, W_low, W_high,
                                   b_high, S, csum, tv, u, Mth, ZH, flag);
  kB<<<NB / 128, 256, 0, stream>>>(hidden, out, Mth, u, csum, ZH, flag, cnt, list,
                                   S, tv, W_low, b_low);
  kC<<<2048, 256, 0, stream>>>(hidden, out, W_low, b_low, S, ZH, cnt, list);
}